// Round 9
// baseline (251.999 us; speedup 1.0000x reference)
//
#include <hip/hip_runtime.h>
#include <math.h>

#define NB 16384
#define DIM 128
#define SUMK 4096
#define KCLS 2048

constexpr float LA = 20.0f;
constexpr float TAU = 0.2f;
constexpr float MARGIN = 0.01f;
constexpr float NPAIRS2 = 8384512.0f;          // 2048*2047*2
constexpr float G2L = 14.426950408889634f;     // GAMMA_INV * log2(e)
#define CS (16 * NB)                           // per-component stride in pw

typedef _Float16 half8 __attribute__((ext_vector_type(8)));
typedef float f32x4 __attribute__((ext_vector_type(4)));

#if __has_builtin(__builtin_amdgcn_exp2f)
#define EXP2(v) __builtin_amdgcn_exp2f(v)
#else
#define EXP2(v) exp2f(v)
#endif

// direct global->LDS DMA, 16B per lane; dst is wave-uniform base (+lane*16 in HW)
#define GLOAD_LDS(SRC, DST)                                                          \
    __builtin_amdgcn_global_load_lds(                                                \
        (const __attribute__((address_space(1))) void*)(SRC),                        \
        (__attribute__((address_space(3))) void*)(DST), 16, 0, 0)

// ---------------------------------------------------------------------------
// knorm: zero accumulators (block 0) + normalize centers -> fp16 cnT[j][d].
// ---------------------------------------------------------------------------
__global__ __launch_bounds__(256) void knorm(const float* __restrict__ fc,
                                             _Float16* __restrict__ cnT,
                                             float* __restrict__ wsz) {
    __shared__ float tile[DIM][35];
    const int t = threadIdx.x;
    if (blockIdx.x == 0) wsz[t] = 0.f;         // replaces hipMemsetAsync node
    const int j0 = blockIdx.x * 32;

    const int jr = t & 31;
    const int dr = t >> 5;
#pragma unroll
    for (int it = 0; it < 16; ++it) {
        int d = it * 8 + dr;
        tile[d][jr] = fc[(size_t)d * SUMK + j0 + jr];
    }
    __syncthreads();

    const int p = t & 7;
    const int j = t >> 3;
    float v[16];
    float ss = 0.f;
#pragma unroll
    for (int i = 0; i < 16; ++i) {
        v[i] = tile[p * 16 + i][j];
        ss = fmaf(v[i], v[i], ss);
    }
    ss += __shfl_xor(ss, 1);
    ss += __shfl_xor(ss, 2);
    ss += __shfl_xor(ss, 4);
    float rn = 1.0f / sqrtf(ss);

    _Float16* w = cnT + (size_t)(j0 + j) * DIM + p * 16;
    half8 h0, h1;
#pragma unroll
    for (int k = 0; k < 8; ++k) {
        h0[k] = (_Float16)(v[k] * rn);
        h1[k] = (_Float16)(v[8 + k] * rn);
    }
    *(half8*)w = h0;
    *(half8*)(w + 8) = h1;
}

// ---------------------------------------------------------------------------
// kbig: ids 0..1023  = kmain (64 rows/wave, 256 rows/block, 256 cols/block,
//                      counted-vmcnt LDS pipeline, fused CE via last-arriver),
//       ids 1024..3071 = kreg. Final loss by the global last-arriver.
// launch_bounds(256,3): VGPR cap ~170 so b[4][4] (64 VGPR) stays in registers.
// ---------------------------------------------------------------------------
__global__ __launch_bounds__(256, 3) void kbig(const float* __restrict__ x,
                                               const _Float16* __restrict__ cnT,
                                               const int* __restrict__ tgt,
                                               float* __restrict__ pw,
                                               float* __restrict__ out,
                                               float* __restrict__ wsf) {
    __shared__ _Float16 smem[3][2][4][64][8];   // 24 KB
    __shared__ float red[4];
    __shared__ unsigned sflag;

    float* acc_ce = wsf;                        // wsf[0]
    float* acc_rg = wsf + 1;                    // wsf[1]
    unsigned* done = (unsigned*)(wsf + 2);      // global arrival counter
    unsigned* rgc  = (unsigned*)(wsf + 3);      // [64] rowgroup counters

    const int t = threadIdx.x;
    const int lane = t & 63;
    const int wid = t >> 6;
    const int m = lane & 15;
    const int kg = lane >> 4;
    const int id = blockIdx.x;

#define FINISH_IF_LAST()                                                      \
    do {                                                                      \
        __threadfence();                                                      \
        unsigned old_ = atomicAdd(done, 1u);                                  \
        if (old_ == 3071u) {                                                  \
            __threadfence();                                                  \
            float ce_ = atomicAdd(acc_ce, 0.f);                               \
            float rg_ = atomicAdd(acc_rg, 0.f);                               \
            out[0] = ce_ / (float)NB + TAU * (rg_ / NPAIRS2);                 \
        }                                                                     \
    } while (0)

    if (id >= 1024) {
        // ---------------- kreg path ----------------
        const int rid = id - 1024;
        const int cls = rid >> 10;
        const int ti = (rid >> 5) & 31;
        const int tj = rid & 31;
        if (tj < ti) {
            if (t == 0) FINISH_IF_LAST();
            return;
        }

        const int i0 = cls * KCLS + ti * 64 + wid * 16;
        const int jb = cls * KCLS + tj * 64;

        const _Float16* aip = cnT + (size_t)(i0 + m) * DIM + kg * 8;
        half8 af[4];
#pragma unroll
        for (int tt = 0; tt < 4; ++tt) af[tt] = *(const half8*)(aip + tt * 32);

        half8 bf[16];
#pragma unroll
        for (int fj = 0; fj < 4; ++fj) {
            const _Float16* bjp = cnT + (size_t)(jb + fj * 16 + m) * DIM + kg * 8;
#pragma unroll
            for (int tt = 0; tt < 4; ++tt) bf[fj * 4 + tt] = *(const half8*)(bjp + tt * 32);
        }

        float local = 0.f;
#pragma unroll
        for (int fj = 0; fj < 4; ++fj) {
            f32x4 cc = {0.f, 0.f, 0.f, 0.f};
#pragma unroll
            for (int tt = 0; tt < 4; ++tt)
                cc = __builtin_amdgcn_mfma_f32_16x16x32_f16(af[tt], bf[fj * 4 + tt], cc, 0, 0, 0);
            int gj = jb + fj * 16 + m;
#pragma unroll
            for (int r = 0; r < 4; ++r) {
                int gi = i0 + kg * 4 + r;
                if (gi < gj)
                    local += sqrtf(fmaxf(2.0f + 1e-5f - 2.f * cc[r], 0.f));
            }
        }
#pragma unroll
        for (int off = 1; off < 64; off <<= 1) local += __shfl_xor(local, off);
        if (lane == 0) red[wid] = local;
        __syncthreads();
        if (t == 0) {
            atomicAdd(acc_rg, (red[0] + red[1]) + (red[2] + red[3]));
            FINISH_IF_LAST();
        }
        return;
    }

    // ---------------- kmain path ----------------
    const int rb = id >> 4;          // 0..63 rowgroup
    const int cls = (id >> 3) & 1;
    const int qz = id & 7;
    const int r0 = rb * 256 + wid * 64;

    // ---- load + normalize 4 x-rows into B fragments ----
    half8 b[4][4];                   // [rowfrag][tt] = 64 VGPR
#define LOADX(ROW, RF)                                                        \
    do {                                                                      \
        const float* xp = x + (size_t)(ROW)*DIM + kg * 8;                     \
        float xr[4][8];                                                       \
        float ss = 0.f;                                                       \
        _Pragma("unroll") for (int tt = 0; tt < 4; ++tt) {                    \
            float4 f0 = *(const float4*)(xp + tt * 32);                       \
            float4 f1 = *(const float4*)(xp + tt * 32 + 4);                   \
            xr[tt][0] = f0.x; xr[tt][1] = f0.y; xr[tt][2] = f0.z;             \
            xr[tt][3] = f0.w; xr[tt][4] = f1.x; xr[tt][5] = f1.y;             \
            xr[tt][6] = f1.z; xr[tt][7] = f1.w;                               \
            _Pragma("unroll") for (int qq = 0; qq < 8; ++qq)                  \
                ss = fmaf(xr[tt][qq], xr[tt][qq], ss);                        \
        }                                                                     \
        ss += __shfl_xor(ss, 16);                                             \
        ss += __shfl_xor(ss, 32);                                             \
        float rn = G2L / sqrtf(ss);                                           \
        _Pragma("unroll") for (int tt = 0; tt < 4; ++tt)                      \
            _Pragma("unroll") for (int qq = 0; qq < 8; ++qq)                  \
                b[RF][tt][qq] = (_Float16)(xr[tt][qq] * rn);                  \
    } while (0)

    LOADX(r0 + m, 0);
    LOADX(r0 + 16 + m, 1);
    LOADX(r0 + 32 + m, 2);
    LOADX(r0 + 48 + m, 3);
#undef LOADX

    // stage assignment: wave wid stages fragment-slices q = wid*2, wid*2+1
    const int q0 = wid * 2, q1 = wid * 2 + 1;
    const int cf0 = q0 >> 2, tt0 = q0 & 3;
    const int cf1 = q1 >> 2, tt1 = q1 & 3;
    const int colbase = cls * KCLS + qz * 256;
    const _Float16* s0 = cnT + (size_t)(colbase + cf0 * 16 + m) * DIM + tt0 * 32 + kg * 8;
    const _Float16* s1 = cnT + (size_t)(colbase + cf1 * 16 + m) * DIM + tt1 * 32 + kg * 8;
    const size_t CSTEP = (size_t)32 * DIM;

#define STAGE(CH, BUF)                                                    \
    do {                                                                  \
        GLOAD_LDS(s0 + (size_t)(CH) * CSTEP, &smem[BUF][cf0][tt0][0][0]); \
        GLOAD_LDS(s1 + (size_t)(CH) * CSTEP, &smem[BUF][cf1][tt1][0][0]); \
    } while (0)

    float rz[4] = {0.f, 0.f, 0.f, 0.f};
    float rw[4] = {0.f, 0.f, 0.f, 0.f};

#define EPI(C, RZ, RW)                                                        \
    do {                                                                      \
        float e0 = EXP2(C[0]);                                                \
        float e1 = EXP2(C[1]);                                                \
        float e2 = EXP2(C[2]);                                                \
        float e3 = EXP2(C[3]);                                                \
        RZ += (e0 + e1) + (e2 + e3);                                          \
        RW += fmaf(e0, C[0], e1 * C[1]) + fmaf(e2, C[2], e3 * C[3]);          \
    } while (0)

#define COMPUTE(B)                                                            \
    do {                                                                      \
        _Pragma("unroll") for (int cf = 0; cf < 2; ++cf) {                    \
            half8 a0 = *(const half8*)&smem[B][cf][0][lane][0];               \
            half8 a1 = *(const half8*)&smem[B][cf][1][lane][0];               \
            half8 a2 = *(const half8*)&smem[B][cf][2][lane][0];               \
            half8 a3 = *(const half8*)&smem[B][cf][3][lane][0];               \
            f32x4 c[4];                                                       \
            __builtin_amdgcn_s_setprio(1);                                    \
            _Pragma("unroll") for (int rf = 0; rf < 4; ++rf) {                \
                f32x4 cc = {0.f, 0.f, 0.f, 0.f};                              \
                cc = __builtin_amdgcn_mfma_f32_16x16x32_f16(a0, b[rf][0], cc, 0, 0, 0); \
                cc = __builtin_amdgcn_mfma_f32_16x16x32_f16(a1, b[rf][1], cc, 0, 0, 0); \
                cc = __builtin_amdgcn_mfma_f32_16x16x32_f16(a2, b[rf][2], cc, 0, 0, 0); \
                cc = __builtin_amdgcn_mfma_f32_16x16x32_f16(a3, b[rf][3], cc, 0, 0, 0); \
                c[rf] = cc;                                                   \
            }                                                                 \
            __builtin_amdgcn_s_setprio(0);                                    \
            _Pragma("unroll") for (int rf = 0; rf < 4; ++rf)                  \
                EPI(c[rf], rz[rf], rw[rf]);                                   \
        }                                                                     \
    } while (0)

    STAGE(0, 0);
    STAGE(1, 1);

    for (int ch = 0; ch < 7; ++ch) {
        asm volatile("s_waitcnt vmcnt(2)" ::: "memory");  // own stage(ch) landed
        __builtin_amdgcn_s_barrier();                     // all stage(ch) landed; prev reads done
        if (ch < 6) STAGE(ch + 2, (ch + 2) % 3);
        COMPUTE(ch % 3);
    }
    asm volatile("s_waitcnt vmcnt(0)" ::: "memory");      // tail: stage(7)
    __builtin_amdgcn_s_barrier();
    COMPUTE(1);                                           // 7 % 3
#undef COMPUTE
#undef EPI
#undef STAGE

    // merge the 4 kg-groups (disjoint center subsets, plain sums)
#pragma unroll
    for (int rf = 0; rf < 4; ++rf) {
        rz[rf] += __shfl_xor(rz[rf], 16); rz[rf] += __shfl_xor(rz[rf], 32);
        rw[rf] += __shfl_xor(rw[rf], 16); rw[rf] += __shfl_xor(rw[rf], 32);
    }

    if (lane < 16) {
        const size_t base = (size_t)(cls * 8 + qz) * NB;
#pragma unroll
        for (int rf = 0; rf < 4; ++rf) {
            const int row = r0 + rf * 16 + m;
            pw[0 * CS + base + row] = rz[rf];
            pw[1 * CS + base + row] = rw[rf];
        }
    }

    // ---- last of the 16 (cls,qz)-blocks for this rowgroup computes CE ----
    __threadfence();
    if (t == 0) {
        unsigned old = atomicAdd(&rgc[rb], 1u);
        unsigned last = (old == 15u) ? 1u : 0u;
        if (last) __threadfence();    // acquire: others' pw stores visible
        sflag = last;
    }
    __syncthreads();
    if (sflag) {
        const int i = rb * 256 + t;
        float z0 = 0.f, w0 = 0.f, z1 = 0.f, w1 = 0.f;
#pragma unroll
        for (int q = 0; q < 8; ++q) {
            z0 += pw[0 * CS + (size_t)q * NB + i];
            w0 += pw[1 * CS + (size_t)q * NB + i];
            z1 += pw[0 * CS + (size_t)(8 + q) * NB + i];
            w1 += pw[1 * CS + (size_t)(8 + q) * NB + i];
        }
        float lg0 = LA * (w0 / (z0 * G2L) - MARGIN);
        float lg1 = LA * (w1 / (z1 * G2L) - MARGIN);
        out[1 + 2 * i] = lg0;
        out[2 + 2 * i] = lg1;
        int tg = tgt[i];
        float mx = fmaxf(lg0, lg1);
        float lse = mx + logf(expf(lg0 - mx) + expf(lg1 - mx));
        float ce = lse - (tg ? lg1 : lg0);
#pragma unroll
        for (int off = 1; off < 64; off <<= 1) ce += __shfl_xor(ce, off);
        if ((t & 63) == 0) red[t >> 6] = ce;
        __syncthreads();
        if (t == 0) atomicAdd(acc_ce, (red[0] + red[1]) + (red[2] + red[3]));
    }
    if (t == 0) FINISH_IF_LAST();
#undef FINISH_IF_LAST
}

extern "C" void kernel_launch(void* const* d_in, const int* in_sizes, int n_in,
                              void* d_out, int out_size, void* d_ws, size_t ws_size,
                              hipStream_t stream) {
    const float* x  = (const float*)d_in[0];
    const int*   tg = (const int*)d_in[1];
    const float* fc = (const float*)d_in[2];
    float* out = (float*)d_out;
    float* ws  = (float*)d_ws;
    // ws layout: [0..255] accum/counters (1 KB), then cnT (1 MB), then pw (2 MB)
    _Float16* cnT = (_Float16*)(ws + 256);
    float* pw = (float*)(cnT + (size_t)SUMK * DIM);

    knorm<<<SUMK / 32, 256, 0, stream>>>(fc, cnT, ws);
    kbig<<<1024 + 2048, 256, 0, stream>>>(x, cnT, tg, pw, out, ws);
}

// Round 10
// 238.628 us; speedup vs baseline: 1.0560x; 1.0560x over previous
//
#include <hip/hip_runtime.h>
#include <math.h>

#define NB 16384
#define DIM 128
#define SUMK 4096
#define KCLS 2048

constexpr float LA = 20.0f;
constexpr float TAU = 0.2f;
constexpr float MARGIN = 0.01f;
constexpr float NPAIRS2 = 8384512.0f;          // 2048*2047*2
constexpr float G2L = 14.426950408889634f;     // GAMMA_INV * log2(e)
#define CSL (8 * NB)                           // per-component stride in pw

typedef _Float16 half8 __attribute__((ext_vector_type(8)));
typedef float f32x4 __attribute__((ext_vector_type(4)));

#if __has_builtin(__builtin_amdgcn_exp2f)
#define EXP2(v) __builtin_amdgcn_exp2f(v)
#else
#define EXP2(v) exp2f(v)
#endif

// direct global->LDS DMA, 16B per lane; dst is wave-uniform base (+lane*16 in HW)
#define GLOAD_LDS(SRC, DST)                                                          \
    __builtin_amdgcn_global_load_lds(                                                \
        (const __attribute__((address_space(1))) void*)(SRC),                        \
        (__attribute__((address_space(3))) void*)(DST), 16, 0, 0)

// ---------------------------------------------------------------------------
// knorm: zero accumulators (block 0) + normalize centers -> fp16 cnT[j][d].
// ---------------------------------------------------------------------------
__global__ __launch_bounds__(256) void knorm(const float* __restrict__ fc,
                                             _Float16* __restrict__ cnT,
                                             float* __restrict__ wsz) {
    __shared__ float tile[DIM][35];
    const int t = threadIdx.x;
    if (blockIdx.x == 0) wsz[t] = 0.f;         // replaces hipMemsetAsync node
    const int j0 = blockIdx.x * 32;

    const int jr = t & 31;
    const int dr = t >> 5;
#pragma unroll
    for (int it = 0; it < 16; ++it) {
        int d = it * 8 + dr;
        tile[d][jr] = fc[(size_t)d * SUMK + j0 + jr];
    }
    __syncthreads();

    const int p = t & 7;
    const int j = t >> 3;
    float v[16];
    float ss = 0.f;
#pragma unroll
    for (int i = 0; i < 16; ++i) {
        v[i] = tile[p * 16 + i][j];
        ss = fmaf(v[i], v[i], ss);
    }
    ss += __shfl_xor(ss, 1);
    ss += __shfl_xor(ss, 2);
    ss += __shfl_xor(ss, 4);
    float rn = 1.0f / sqrtf(ss);

    _Float16* w = cnT + (size_t)(j0 + j) * DIM + p * 16;
    half8 h0, h1;
#pragma unroll
    for (int k = 0; k < 8; ++k) {
        h0[k] = (_Float16)(v[k] * rn);
        h1[k] = (_Float16)(v[8 + k] * rn);
    }
    *(half8*)w = h0;
    *(half8*)(w + 8) = h1;
}

// ---------------------------------------------------------------------------
// kbig: ids 0..1023  = kmain: 128 rows x 512 cols per block (4 waves x 32 rows),
//       8 chunks of 64 cols; accumulate-then-epilogue (acc in MFMA C regs),
//       counted-vmcnt triple-buffer LDS pipeline; fused CE via last-arriver.
//       ids 1024..3071 = kreg. Final loss by the global last-arriver.
// ---------------------------------------------------------------------------
__global__ __launch_bounds__(256, 3) void kbig(const float* __restrict__ x,
                                               const _Float16* __restrict__ cnT,
                                               const int* __restrict__ tgt,
                                               float* __restrict__ pw,
                                               float* __restrict__ out,
                                               float* __restrict__ wsf) {
    __shared__ _Float16 smem[3][4][4][64][8];   // [buf][cf][ks][lane][8h] = 48 KB
    __shared__ float red[4];
    __shared__ unsigned sflag;

    float* acc_ce = wsf;                        // wsf[0]
    float* acc_rg = wsf + 1;                    // wsf[1]
    unsigned* done = (unsigned*)(wsf + 2);      // global arrival counter
    unsigned* rgc  = (unsigned*)(wsf + 3);      // [128] rowgroup counters

    const int t = threadIdx.x;
    const int lane = t & 63;
    const int wid = t >> 6;
    const int m = lane & 15;
    const int kg = lane >> 4;
    const int id = blockIdx.x;

#define FINISH_IF_LAST()                                                      \
    do {                                                                      \
        __threadfence();                                                      \
        unsigned old_ = atomicAdd(done, 1u);                                  \
        if (old_ == 3071u) {                                                  \
            __threadfence();                                                  \
            float ce_ = atomicAdd(acc_ce, 0.f);                               \
            float rg_ = atomicAdd(acc_rg, 0.f);                               \
            out[0] = ce_ / (float)NB + TAU * (rg_ / NPAIRS2);                 \
        }                                                                     \
    } while (0)

    if (id >= 1024) {
        // ---------------- kreg path ----------------
        const int rid = id - 1024;
        const int cls = rid >> 10;
        const int ti = (rid >> 5) & 31;
        const int tj = rid & 31;
        if (tj < ti) {
            if (t == 0) FINISH_IF_LAST();
            return;
        }

        const int i0 = cls * KCLS + ti * 64 + wid * 16;
        const int jb = cls * KCLS + tj * 64;

        const _Float16* aip = cnT + (size_t)(i0 + m) * DIM + kg * 8;
        half8 af[4];
#pragma unroll
        for (int tt = 0; tt < 4; ++tt) af[tt] = *(const half8*)(aip + tt * 32);

        half8 bf[16];
#pragma unroll
        for (int fj = 0; fj < 4; ++fj) {
            const _Float16* bjp = cnT + (size_t)(jb + fj * 16 + m) * DIM + kg * 8;
#pragma unroll
            for (int tt = 0; tt < 4; ++tt) bf[fj * 4 + tt] = *(const half8*)(bjp + tt * 32);
        }

        float local = 0.f;
#pragma unroll
        for (int fj = 0; fj < 4; ++fj) {
            f32x4 cc = {0.f, 0.f, 0.f, 0.f};
#pragma unroll
            for (int tt = 0; tt < 4; ++tt)
                cc = __builtin_amdgcn_mfma_f32_16x16x32_f16(af[tt], bf[fj * 4 + tt], cc, 0, 0, 0);
            int gj = jb + fj * 16 + m;
#pragma unroll
            for (int r = 0; r < 4; ++r) {
                int gi = i0 + kg * 4 + r;
                if (gi < gj)
                    local += sqrtf(fmaxf(2.0f + 1e-5f - 2.f * cc[r], 0.f));
            }
        }
#pragma unroll
        for (int off = 1; off < 64; off <<= 1) local += __shfl_xor(local, off);
        if (lane == 0) red[wid] = local;
        __syncthreads();
        if (t == 0) {
            atomicAdd(acc_rg, (red[0] + red[1]) + (red[2] + red[3]));
            FINISH_IF_LAST();
        }
        return;
    }

    // ---------------- kmain path ----------------
    const int rb = id >> 3;            // 0..127 rowgroup (128 rows)
    const int split = id & 7;          // 0..7: cls = split>>2, qz = split&3
    const int cls = split >> 2;
    const int qz = split & 3;
    const int r0 = rb * 128 + wid * 32;

    // ---- load + normalize 2 x-rows into B fragments (32 VGPR, R7-proven) ----
    half8 b[2][4];                     // [rowfrag][ks]
#define LOADX(ROW, RF)                                                        \
    do {                                                                      \
        const float* xp = x + (size_t)(ROW)*DIM + kg * 8;                     \
        float xr[4][8];                                                       \
        float ss = 0.f;                                                       \
        _Pragma("unroll") for (int ks = 0; ks < 4; ++ks) {                    \
            float4 f0 = *(const float4*)(xp + ks * 32);                       \
            float4 f1 = *(const float4*)(xp + ks * 32 + 4);                   \
            xr[ks][0] = f0.x; xr[ks][1] = f0.y; xr[ks][2] = f0.z;             \
            xr[ks][3] = f0.w; xr[ks][4] = f1.x; xr[ks][5] = f1.y;             \
            xr[ks][6] = f1.z; xr[ks][7] = f1.w;                               \
            _Pragma("unroll") for (int qq = 0; qq < 8; ++qq)                  \
                ss = fmaf(xr[ks][qq], xr[ks][qq], ss);                        \
        }                                                                     \
        ss += __shfl_xor(ss, 16);                                             \
        ss += __shfl_xor(ss, 32);                                             \
        float rn = G2L / sqrtf(ss);                                           \
        _Pragma("unroll") for (int ks = 0; ks < 4; ++ks)                      \
            _Pragma("unroll") for (int qq = 0; qq < 8; ++qq)                  \
                b[RF][ks][qq] = (_Float16)(xr[ks][qq] * rn);                  \
    } while (0)

    LOADX(r0 + m, 0);
    LOADX(r0 + 16 + m, 1);
#undef LOADX
    // drain x loads so in-loop vmcnt counts ONLY stage DMAs
    asm volatile("s_waitcnt vmcnt(0)" ::: "memory");

    // ---- staging: wave wid stages col-frag cf=wid of each chunk ----
    const int colbase = cls * KCLS + qz * 512;
    const _Float16* sA = cnT + (size_t)(colbase + wid * 16 + m) * DIM + kg * 8;
    const size_t CSTEP = (size_t)64 * DIM;     // 64 cols of halves

#define STAGE(CH, BUF)                                                        \
    do {                                                                      \
        _Pragma("unroll") for (int ks = 0; ks < 4; ++ks)                      \
            GLOAD_LDS(sA + (size_t)(CH) * CSTEP + ks * 32,                    \
                      &smem[BUF][wid][ks][0][0]);                             \
    } while (0)

    float zac[2] = {0.f, 0.f};
    float wac[2] = {0.f, 0.f};

#define COMPUTE(B)                                                            \
    do {                                                                      \
        f32x4 c[2][4];                                                        \
        _Pragma("unroll") for (int rf = 0; rf < 2; ++rf)                      \
            _Pragma("unroll") for (int cf = 0; cf < 4; ++cf)                  \
                c[rf][cf] = (f32x4){0.f, 0.f, 0.f, 0.f};                      \
        __builtin_amdgcn_s_setprio(1);                                        \
        _Pragma("unroll") for (int ks = 0; ks < 4; ++ks) {                    \
            half8 a0 = *(const half8*)&smem[B][0][ks][lane][0];               \
            half8 a1 = *(const half8*)&smem[B][1][ks][lane][0];               \
            half8 a2 = *(const half8*)&smem[B][2][ks][lane][0];               \
            half8 a3 = *(const half8*)&smem[B][3][ks][lane][0];               \
            c[0][0] = __builtin_amdgcn_mfma_f32_16x16x32_f16(a0, b[0][ks], c[0][0], 0, 0, 0); \
            c[1][0] = __builtin_amdgcn_mfma_f32_16x16x32_f16(a0, b[1][ks], c[1][0], 0, 0, 0); \
            c[0][1] = __builtin_amdgcn_mfma_f32_16x16x32_f16(a1, b[0][ks], c[0][1], 0, 0, 0); \
            c[1][1] = __builtin_amdgcn_mfma_f32_16x16x32_f16(a1, b[1][ks], c[1][1], 0, 0, 0); \
            c[0][2] = __builtin_amdgcn_mfma_f32_16x16x32_f16(a2, b[0][ks], c[0][2], 0, 0, 0); \
            c[1][2] = __builtin_amdgcn_mfma_f32_16x16x32_f16(a2, b[1][ks], c[1][2], 0, 0, 0); \
            c[0][3] = __builtin_amdgcn_mfma_f32_16x16x32_f16(a3, b[0][ks], c[0][3], 0, 0, 0); \
            c[1][3] = __builtin_amdgcn_mfma_f32_16x16x32_f16(a3, b[1][ks], c[1][3], 0, 0, 0); \
        }                                                                     \
        __builtin_amdgcn_s_setprio(0);                                        \
        _Pragma("unroll") for (int rf = 0; rf < 2; ++rf) {                    \
            _Pragma("unroll") for (int cf = 0; cf < 4; ++cf) {                \
                float s0 = c[rf][cf][0], s1 = c[rf][cf][1];                   \
                float s2 = c[rf][cf][2], s3 = c[rf][cf][3];                   \
                float e0 = EXP2(s0), e1 = EXP2(s1);                           \
                float e2 = EXP2(s2), e3 = EXP2(s3);                           \
                zac[rf] += (e0 + e1) + (e2 + e3);                             \
                wac[rf] += fmaf(e0, s0, e1 * s1) + fmaf(e2, s2, e3 * s3);     \
            }                                                                 \
        }                                                                     \
    } while (0)

    STAGE(0, 0);
    STAGE(1, 1);

    for (int ch = 0; ch < 7; ++ch) {
        asm volatile("s_waitcnt vmcnt(4)" ::: "memory");  // own stage(ch) landed
        __builtin_amdgcn_s_barrier();                     // all stage(ch) landed; prev reads done
        if (ch < 6) STAGE(ch + 2, (ch + 2) % 3);
        COMPUTE(ch % 3);
    }
    asm volatile("s_waitcnt vmcnt(0)" ::: "memory");      // tail: stage(7)
    __builtin_amdgcn_s_barrier();
    COMPUTE(1);                                           // 7 % 3
#undef COMPUTE
#undef STAGE

    // merge the 4 kg-groups (disjoint 4-col subsets per fragment, plain sums)
#pragma unroll
    for (int rf = 0; rf < 2; ++rf) {
        zac[rf] += __shfl_xor(zac[rf], 16); zac[rf] += __shfl_xor(zac[rf], 32);
        wac[rf] += __shfl_xor(wac[rf], 16); wac[rf] += __shfl_xor(wac[rf], 32);
    }

    if (lane < 16) {
        const size_t base = (size_t)split * NB;
#pragma unroll
        for (int rf = 0; rf < 2; ++rf) {
            const int row = r0 + rf * 16 + m;
            pw[0 * CSL + base + row] = zac[rf];
            pw[1 * CSL + base + row] = wac[rf];
        }
    }

    // ---- last of the 8 split-blocks for this rowgroup computes CE ----
    __threadfence();
    if (t == 0) {
        unsigned old = atomicAdd(&rgc[rb], 1u);
        unsigned last = (old == 7u) ? 1u : 0u;
        if (last) __threadfence();    // acquire: others' pw stores visible
        sflag = last;
    }
    __syncthreads();
    if (sflag) {
        float ce = 0.f;
        if (t < 128) {
            const int i = rb * 128 + t;
            float z0 = 0.f, w0 = 0.f, z1 = 0.f, w1 = 0.f;
#pragma unroll
            for (int q = 0; q < 4; ++q) {
                z0 += pw[0 * CSL + (size_t)q * NB + i];
                w0 += pw[1 * CSL + (size_t)q * NB + i];
                z1 += pw[0 * CSL + (size_t)(4 + q) * NB + i];
                w1 += pw[1 * CSL + (size_t)(4 + q) * NB + i];
            }
            float lg0 = LA * (w0 / (z0 * G2L) - MARGIN);
            float lg1 = LA * (w1 / (z1 * G2L) - MARGIN);
            out[1 + 2 * i] = lg0;
            out[2 + 2 * i] = lg1;
            int tg = tgt[i];
            float mx = fmaxf(lg0, lg1);
            float lse = mx + logf(expf(lg0 - mx) + expf(lg1 - mx));
            ce = lse - (tg ? lg1 : lg0);
        }
#pragma unroll
        for (int off = 1; off < 64; off <<= 1) ce += __shfl_xor(ce, off);
        if ((t & 63) == 0) red[t >> 6] = ce;
        __syncthreads();
        if (t == 0) atomicAdd(acc_ce, red[0] + red[1]);   // waves 2,3 contributed 0
    }
    if (t == 0) FINISH_IF_LAST();
#undef FINISH_IF_LAST
}

extern "C" void kernel_launch(void* const* d_in, const int* in_sizes, int n_in,
                              void* d_out, int out_size, void* d_ws, size_t ws_size,
                              hipStream_t stream) {
    const float* x  = (const float*)d_in[0];
    const int*   tg = (const int*)d_in[1];
    const float* fc = (const float*)d_in[2];
    float* out = (float*)d_out;
    float* ws  = (float*)d_ws;
    // ws layout: [0..255] accum/counters (1 KB), then cnT (1 MB), then pw (1 MB)
    _Float16* cnT = (_Float16*)(ws + 256);
    float* pw = (float*)(cnT + (size_t)SUMK * DIM);

    knorm<<<SUMK / 32, 256, 0, stream>>>(fc, cnT, ws);
    kbig<<<1024 + 2048, 256, 0, stream>>>(x, cnT, tg, pw, out, ws);
}

// Round 11
// 136.161 us; speedup vs baseline: 1.8507x; 1.7525x over previous
//
#include <hip/hip_runtime.h>
#include <math.h>

#define NB 16384
#define DIM 128
#define SUMK 4096
#define KCLS 2048

constexpr float LA = 20.0f;
constexpr float TAU = 0.2f;
constexpr float MARGIN = 0.01f;
constexpr float NPAIRS2 = 8384512.0f;          // 2048*2047*2
constexpr float G2L = 14.426950408889634f;     // GAMMA_INV * log2(e)

typedef _Float16 half8 __attribute__((ext_vector_type(8)));
typedef float f32x4 __attribute__((ext_vector_type(4)));

#if __has_builtin(__builtin_amdgcn_exp2f)
#define EXP2(v) __builtin_amdgcn_exp2f(v)
#else
#define EXP2(v) exp2f(v)
#endif

#define ALOAD(P) __hip_atomic_load((P), __ATOMIC_RELAXED, __HIP_MEMORY_SCOPE_AGENT)

// direct global->LDS DMA, 16B per lane; dst is wave-uniform base (+lane*16 in HW)
#define GLOAD_LDS(SRC, DST)                                                          \
    __builtin_amdgcn_global_load_lds(                                                \
        (const __attribute__((address_space(1))) void*)(SRC),                        \
        (__attribute__((address_space(3))) void*)(DST), 16, 0, 0)

// ---------------------------------------------------------------------------
// knorm: zero accumulators + pw (replaces memset), normalize centers -> cnT.
// ---------------------------------------------------------------------------
__global__ __launch_bounds__(256) void knorm(const float* __restrict__ fc,
                                             _Float16* __restrict__ cnT,
                                             float* __restrict__ wsz,
                                             float* __restrict__ pwz) {
    __shared__ float tile[DIM][35];
    const int t = threadIdx.x;
    if (blockIdx.x == 0) wsz[t] = 0.f;
    pwz[blockIdx.x * 512 + t] = 0.f;           // zero pw: 128 blocks x 512
    pwz[blockIdx.x * 512 + 256 + t] = 0.f;
    const int j0 = blockIdx.x * 32;

    const int jr = t & 31;
    const int dr = t >> 5;
#pragma unroll
    for (int it = 0; it < 16; ++it) {
        int d = it * 8 + dr;
        tile[d][jr] = fc[(size_t)d * SUMK + j0 + jr];
    }
    __syncthreads();

    const int p = t & 7;
    const int j = t >> 3;
    float v[16];
    float ss = 0.f;
#pragma unroll
    for (int i = 0; i < 16; ++i) {
        v[i] = tile[p * 16 + i][j];
        ss = fmaf(v[i], v[i], ss);
    }
    ss += __shfl_xor(ss, 1);
    ss += __shfl_xor(ss, 2);
    ss += __shfl_xor(ss, 4);
    float rn = 1.0f / sqrtf(ss);

    _Float16* w = cnT + (size_t)(j0 + j) * DIM + p * 16;
    half8 h0, h1;
#pragma unroll
    for (int k = 0; k < 8; ++k) {
        h0[k] = (_Float16)(v[k] * rn);
        h1[k] = (_Float16)(v[8 + k] * rn);
    }
    *(half8*)w = h0;
    *(half8*)(w + 8) = h1;
}

// ---------------------------------------------------------------------------
// kbig: ids 0..1023 = kmain (128 rows x 512 cols, accumulate-then-epilogue,
//       counted-vmcnt LDS pipeline; partials atomic-accumulated into pw;
//       per-rowgroup last-arriver computes CE). ids 1024..3071 = kreg.
// NO __threadfence anywhere: cross-block ordering = vmcnt(0) drain + atomics;
// cross-block reads = agent-scope atomic loads. (threadfence's L2 invalidate
// was the R8-R10 4x regression.)
// ---------------------------------------------------------------------------
__global__ __launch_bounds__(256, 3) void kbig(const float* __restrict__ x,
                                               const _Float16* __restrict__ cnT,
                                               const int* __restrict__ tgt,
                                               float* __restrict__ pw,
                                               float* __restrict__ out,
                                               float* __restrict__ wsf) {
    __shared__ _Float16 smem[3][4][4][64][8];   // [buf][cf][ks][lane][8h] = 48 KB
    __shared__ float red[4];
    __shared__ unsigned sflag;

    float* acc_ce = wsf;                        // wsf[0]
    float* acc_rg = wsf + 1;                    // wsf[1]
    unsigned* done = (unsigned*)(wsf + 2);      // global arrival counter
    unsigned* rgc  = (unsigned*)(wsf + 3);      // [128] rowgroup counters

    const int t = threadIdx.x;
    const int lane = t & 63;
    const int wid = t >> 6;
    const int m = lane & 15;
    const int kg = lane >> 4;
    const int id = blockIdx.x;

#define FINISH_IF_LAST()                                                      \
    do {                                                                      \
        asm volatile("s_waitcnt vmcnt(0)" ::: "memory");                      \
        unsigned old_ = atomicAdd(done, 1u);                                  \
        if (old_ == 3071u) {                                                  \
            float ce_ = ALOAD(acc_ce);                                        \
            float rg_ = ALOAD(acc_rg);                                        \
            out[0] = ce_ / (float)NB + TAU * (rg_ / NPAIRS2);                 \
        }                                                                     \
    } while (0)

    if (id >= 1024) {
        // ---------------- kreg path ----------------
        const int rid = id - 1024;
        const int cls = rid >> 10;
        const int ti = (rid >> 5) & 31;
        const int tj = rid & 31;
        if (tj < ti) {
            if (t == 0) FINISH_IF_LAST();
            return;
        }

        const int i0 = cls * KCLS + ti * 64 + wid * 16;
        const int jb = cls * KCLS + tj * 64;

        const _Float16* aip = cnT + (size_t)(i0 + m) * DIM + kg * 8;
        half8 af[4];
#pragma unroll
        for (int tt = 0; tt < 4; ++tt) af[tt] = *(const half8*)(aip + tt * 32);

        half8 bf[16];
#pragma unroll
        for (int fj = 0; fj < 4; ++fj) {
            const _Float16* bjp = cnT + (size_t)(jb + fj * 16 + m) * DIM + kg * 8;
#pragma unroll
            for (int tt = 0; tt < 4; ++tt) bf[fj * 4 + tt] = *(const half8*)(bjp + tt * 32);
        }

        float local = 0.f;
#pragma unroll
        for (int fj = 0; fj < 4; ++fj) {
            f32x4 cc = {0.f, 0.f, 0.f, 0.f};
#pragma unroll
            for (int tt = 0; tt < 4; ++tt)
                cc = __builtin_amdgcn_mfma_f32_16x16x32_f16(af[tt], bf[fj * 4 + tt], cc, 0, 0, 0);
            int gj = jb + fj * 16 + m;
#pragma unroll
            for (int r = 0; r < 4; ++r) {
                int gi = i0 + kg * 4 + r;
                if (gi < gj)
                    local += sqrtf(fmaxf(2.0f + 1e-5f - 2.f * cc[r], 0.f));
            }
        }
#pragma unroll
        for (int off = 1; off < 64; off <<= 1) local += __shfl_xor(local, off);
        if (lane == 0) red[wid] = local;
        __syncthreads();
        if (t == 0) {
            atomicAdd(acc_rg, (red[0] + red[1]) + (red[2] + red[3]));
            FINISH_IF_LAST();
        }
        return;
    }

    // ---------------- kmain path ----------------
    const int rb = id >> 3;            // 0..127 rowgroup (128 rows)
    const int split = id & 7;          // cls = split>>2, qz = split&3
    const int cls = split >> 2;
    const int qz = split & 3;
    const int r0 = rb * 128 + wid * 32;

    // ---- load + normalize 2 x-rows into B fragments ----
    half8 b[2][4];                     // [rowfrag][ks]
#define LOADX(ROW, RF)                                                        \
    do {                                                                      \
        const float* xp = x + (size_t)(ROW)*DIM + kg * 8;                     \
        float xr[4][8];                                                       \
        float ss = 0.f;                                                       \
        _Pragma("unroll") for (int ks = 0; ks < 4; ++ks) {                    \
            float4 f0 = *(const float4*)(xp + ks * 32);                       \
            float4 f1 = *(const float4*)(xp + ks * 32 + 4);                   \
            xr[ks][0] = f0.x; xr[ks][1] = f0.y; xr[ks][2] = f0.z;             \
            xr[ks][3] = f0.w; xr[ks][4] = f1.x; xr[ks][5] = f1.y;             \
            xr[ks][6] = f1.z; xr[ks][7] = f1.w;                               \
            _Pragma("unroll") for (int qq = 0; qq < 8; ++qq)                  \
                ss = fmaf(xr[ks][qq], xr[ks][qq], ss);                        \
        }                                                                     \
        ss += __shfl_xor(ss, 16);                                             \
        ss += __shfl_xor(ss, 32);                                             \
        float rn = G2L / sqrtf(ss);                                           \
        _Pragma("unroll") for (int ks = 0; ks < 4; ++ks)                      \
            _Pragma("unroll") for (int qq = 0; qq < 8; ++qq)                  \
                b[RF][ks][qq] = (_Float16)(xr[ks][qq] * rn);                  \
    } while (0)

    LOADX(r0 + m, 0);
    LOADX(r0 + 16 + m, 1);
#undef LOADX
    // drain x loads so in-loop vmcnt counts ONLY stage DMAs
    asm volatile("s_waitcnt vmcnt(0)" ::: "memory");

    // ---- staging: wave wid stages col-frag cf=wid of each chunk ----
    const int colbase = cls * KCLS + qz * 512;
    const _Float16* sA = cnT + (size_t)(colbase + wid * 16 + m) * DIM + kg * 8;
    const size_t CSTEP = (size_t)64 * DIM;     // 64 cols of halves

#define STAGE(CH, BUF)                                                        \
    do {                                                                      \
        _Pragma("unroll") for (int ks = 0; ks < 4; ++ks)                      \
            GLOAD_LDS(sA + (size_t)(CH) * CSTEP + ks * 32,                    \
                      &smem[BUF][wid][ks][0][0]);                             \
    } while (0)

    float zac[2] = {0.f, 0.f};
    float wac[2] = {0.f, 0.f};

#define COMPUTE(B)                                                            \
    do {                                                                      \
        f32x4 c[2][4];                                                        \
        _Pragma("unroll") for (int rf = 0; rf < 2; ++rf)                      \
            _Pragma("unroll") for (int cf = 0; cf < 4; ++cf)                  \
                c[rf][cf] = (f32x4){0.f, 0.f, 0.f, 0.f};                      \
        __builtin_amdgcn_s_setprio(1);                                        \
        _Pragma("unroll") for (int ks = 0; ks < 4; ++ks) {                    \
            half8 a0 = *(const half8*)&smem[B][0][ks][lane][0];               \
            half8 a1 = *(const half8*)&smem[B][1][ks][lane][0];               \
            half8 a2 = *(const half8*)&smem[B][2][ks][lane][0];               \
            half8 a3 = *(const half8*)&smem[B][3][ks][lane][0];               \
            c[0][0] = __builtin_amdgcn_mfma_f32_16x16x32_f16(a0, b[0][ks], c[0][0], 0, 0, 0); \
            c[1][0] = __builtin_amdgcn_mfma_f32_16x16x32_f16(a0, b[1][ks], c[1][0], 0, 0, 0); \
            c[0][1] = __builtin_amdgcn_mfma_f32_16x16x32_f16(a1, b[0][ks], c[0][1], 0, 0, 0); \
            c[1][1] = __builtin_amdgcn_mfma_f32_16x16x32_f16(a1, b[1][ks], c[1][1], 0, 0, 0); \
            c[0][2] = __builtin_amdgcn_mfma_f32_16x16x32_f16(a2, b[0][ks], c[0][2], 0, 0, 0); \
            c[1][2] = __builtin_amdgcn_mfma_f32_16x16x32_f16(a2, b[1][ks], c[1][2], 0, 0, 0); \
            c[0][3] = __builtin_amdgcn_mfma_f32_16x16x32_f16(a3, b[0][ks], c[0][3], 0, 0, 0); \
            c[1][3] = __builtin_amdgcn_mfma_f32_16x16x32_f16(a3, b[1][ks], c[1][3], 0, 0, 0); \
        }                                                                     \
        __builtin_amdgcn_s_setprio(0);                                        \
        _Pragma("unroll") for (int rf = 0; rf < 2; ++rf) {                    \
            _Pragma("unroll") for (int cf = 0; cf < 4; ++cf) {                \
                float s0 = c[rf][cf][0], s1 = c[rf][cf][1];                   \
                float s2 = c[rf][cf][2], s3 = c[rf][cf][3];                   \
                float e0 = EXP2(s0), e1 = EXP2(s1);                           \
                float e2 = EXP2(s2), e3 = EXP2(s3);                           \
                zac[rf] += (e0 + e1) + (e2 + e3);                             \
                wac[rf] += fmaf(e0, s0, e1 * s1) + fmaf(e2, s2, e3 * s3);     \
            }                                                                 \
        }                                                                     \
    } while (0)

    STAGE(0, 0);
    STAGE(1, 1);

    for (int ch = 0; ch < 7; ++ch) {
        asm volatile("s_waitcnt vmcnt(4)" ::: "memory");  // own stage(ch) landed
        __builtin_amdgcn_s_barrier();                     // all stage(ch) landed; prev reads done
        if (ch < 6) STAGE(ch + 2, (ch + 2) % 3);
        COMPUTE(ch % 3);
    }
    asm volatile("s_waitcnt vmcnt(0)" ::: "memory");      // tail: stage(7)
    __builtin_amdgcn_s_barrier();
    COMPUTE(1);                                           // 7 % 3
#undef COMPUTE
#undef STAGE

    // merge the 4 kg-groups (disjoint col subsets, plain sums)
#pragma unroll
    for (int rf = 0; rf < 2; ++rf) {
        zac[rf] += __shfl_xor(zac[rf], 16); zac[rf] += __shfl_xor(zac[rf], 32);
        wac[rf] += __shfl_xor(wac[rf], 16); wac[rf] += __shfl_xor(wac[rf], 32);
    }

    // ---- atomic-accumulate partials: pw[(cls*2+comp)*NB + row] ----
    if (lane < 16) {
#pragma unroll
        for (int rf = 0; rf < 2; ++rf) {
            const int row = r0 + rf * 16 + m;
            atomicAdd(&pw[(size_t)(cls * 2 + 0) * NB + row], zac[rf]);
            atomicAdd(&pw[(size_t)(cls * 2 + 1) * NB + row], wac[rf]);
        }
    }
    asm volatile("s_waitcnt vmcnt(0)" ::: "memory");      // own atomics applied
    __syncthreads();                                      // all waves' atomics applied

    // ---- last of the 8 split-blocks for this rowgroup computes CE ----
    if (t == 0) {
        unsigned old = atomicAdd(&rgc[rb], 1u);
        sflag = (old == 7u) ? 1u : 0u;
    }
    __syncthreads();
    if (sflag) {
        float ce = 0.f;
        if (t < 128) {
            const int i = rb * 128 + t;
            float z0 = ALOAD(&pw[(size_t)0 * NB + i]);
            float w0 = ALOAD(&pw[(size_t)1 * NB + i]);
            float z1 = ALOAD(&pw[(size_t)2 * NB + i]);
            float w1 = ALOAD(&pw[(size_t)3 * NB + i]);
            float lg0 = LA * (w0 / (z0 * G2L) - MARGIN);
            float lg1 = LA * (w1 / (z1 * G2L) - MARGIN);
            out[1 + 2 * i] = lg0;
            out[2 + 2 * i] = lg1;
            int tg = tgt[i];
            float mx = fmaxf(lg0, lg1);
            float lse = mx + logf(expf(lg0 - mx) + expf(lg1 - mx));
            ce = lse - (tg ? lg1 : lg0);
        }
#pragma unroll
        for (int off = 1; off < 64; off <<= 1) ce += __shfl_xor(ce, off);
        if ((t & 63) == 0) red[t >> 6] = ce;
        __syncthreads();
        if (t == 0) atomicAdd(acc_ce, red[0] + red[1]);   // waves 2,3 are 0
    }
    if (t == 0) FINISH_IF_LAST();
#undef FINISH_IF_LAST
}

extern "C" void kernel_launch(void* const* d_in, const int* in_sizes, int n_in,
                              void* d_out, int out_size, void* d_ws, size_t ws_size,
                              hipStream_t stream) {
    const float* x  = (const float*)d_in[0];
    const int*   tg = (const int*)d_in[1];
    const float* fc = (const float*)d_in[2];
    float* out = (float*)d_out;
    float* ws  = (float*)d_ws;
    // ws layout: [0..255] accum/counters (1 KB), then cnT (1 MB), then pw (256 KB)
    _Float16* cnT = (_Float16*)(ws + 256);
    float* pw = (float*)(cnT + (size_t)SUMK * DIM);

    knorm<<<SUMK / 32, 256, 0, stream>>>(fc, cnT, ws, pw);
    kbig<<<1024 + 2048, 256, 0, stream>>>(x, cnT, tg, pw, out, ws);
}

// Round 12
// 124.416 us; speedup vs baseline: 2.0255x; 1.0944x over previous
//
#include <hip/hip_runtime.h>
#include <math.h>

#define NB 16384
#define DIM 128
#define SUMK 4096
#define KCLS 2048

constexpr float LA = 20.0f;
constexpr float TAU = 0.2f;
constexpr float MARGIN = 0.01f;
constexpr float NPAIRS2 = 8384512.0f;          // 2048*2047*2
constexpr float G2L = 14.426950408889634f;     // GAMMA_INV * log2(e)

typedef _Float16 half8 __attribute__((ext_vector_type(8)));
typedef float f32x4 __attribute__((ext_vector_type(4)));

#if __has_builtin(__builtin_amdgcn_exp2f)
#define EXP2(v) __builtin_amdgcn_exp2f(v)
#else
#define EXP2(v) exp2f(v)
#endif

#define ALOAD(P) __hip_atomic_load((P), __ATOMIC_RELAXED, __HIP_MEMORY_SCOPE_AGENT)

// direct global->LDS DMA, 16B per lane; dst is wave-uniform base (+lane*16 in HW)
#define GLOAD_LDS(SRC, DST)                                                          \
    __builtin_amdgcn_global_load_lds(                                                \
        (const __attribute__((address_space(1))) void*)(SRC),                        \
        (__attribute__((address_space(3))) void*)(DST), 16, 0, 0)

// ---------------------------------------------------------------------------
// knorm: zero accumulators + pw (replaces memset), normalize centers -> cnT.
// ---------------------------------------------------------------------------
__global__ __launch_bounds__(256) void knorm(const float* __restrict__ fc,
                                             _Float16* __restrict__ cnT,
                                             float* __restrict__ wsz,
                                             float* __restrict__ pwz) {
    __shared__ float tile[DIM][35];
    const int t = threadIdx.x;
    if (blockIdx.x == 0) wsz[t] = 0.f;
    pwz[blockIdx.x * 512 + t] = 0.f;           // zero pw: 128 blocks x 512
    pwz[blockIdx.x * 512 + 256 + t] = 0.f;
    const int j0 = blockIdx.x * 32;

    const int jr = t & 31;
    const int dr = t >> 5;
#pragma unroll
    for (int it = 0; it < 16; ++it) {
        int d = it * 8 + dr;
        tile[d][jr] = fc[(size_t)d * SUMK + j0 + jr];
    }
    __syncthreads();

    const int p = t & 7;
    const int j = t >> 3;
    float v[16];
    float ss = 0.f;
#pragma unroll
    for (int i = 0; i < 16; ++i) {
        v[i] = tile[p * 16 + i][j];
        ss = fmaf(v[i], v[i], ss);
    }
    ss += __shfl_xor(ss, 1);
    ss += __shfl_xor(ss, 2);
    ss += __shfl_xor(ss, 4);
    float rn = 1.0f / sqrtf(ss);

    _Float16* w = cnT + (size_t)(j0 + j) * DIM + p * 16;
    half8 h0, h1;
#pragma unroll
    for (int k = 0; k < 8; ++k) {
        h0[k] = (_Float16)(v[k] * rn);
        h1[k] = (_Float16)(v[8 + k] * rn);
    }
    *(half8*)w = h0;
    *(half8*)(w + 8) = h1;
}

// ---------------------------------------------------------------------------
// kbig: ids 0..1023 = kmain; ids 1024..2079 = kreg (triangular-compacted).
// kmain XCD-aware mapping: rb = id & 127, split = id >> 7 -> the 8 blocks
// sharing x-rows are 128 apart == same id mod 8 == SAME XCD (x L2-hits);
// consecutive same-XCD blocks share the same 256KB cnT slab (slab L2-hits).
// 2-buffer LDS (32 KB) + one barrier per chunk; accumulate-then-epilogue.
// ---------------------------------------------------------------------------
__global__ __launch_bounds__(256, 4) void kbig(const float* __restrict__ x,
                                               const _Float16* __restrict__ cnT,
                                               const int* __restrict__ tgt,
                                               float* __restrict__ pw,
                                               float* __restrict__ out,
                                               float* __restrict__ wsf) {
    __shared__ _Float16 smem[2][4][4][64][8];   // [buf][cf][ks][lane][8h] = 32 KB
    __shared__ float red[4];
    __shared__ unsigned sflag;

    float* acc_ce = wsf;                        // wsf[0]
    float* acc_rg = wsf + 1;                    // wsf[1]
    unsigned* done = (unsigned*)(wsf + 2);      // global arrival counter
    unsigned* rgc  = (unsigned*)(wsf + 3);      // [128] rowgroup counters

    const int t = threadIdx.x;
    const int lane = t & 63;
    const int wid = t >> 6;
    const int m = lane & 15;
    const int kg = lane >> 4;
    const int id = blockIdx.x;

#define FINISH_IF_LAST()                                                      \
    do {                                                                      \
        asm volatile("s_waitcnt vmcnt(0)" ::: "memory");                      \
        unsigned old_ = atomicAdd(done, 1u);                                  \
        if (old_ == 2079u) {                                                  \
            float ce_ = ALOAD(acc_ce);                                        \
            float rg_ = ALOAD(acc_rg);                                        \
            out[0] = ce_ / (float)NB + TAU * (rg_ / NPAIRS2);                 \
        }                                                                     \
    } while (0)

    if (id >= 1024) {
        // ---------------- kreg path (triangular-compacted) ----------------
        const int rid = id - 1024;              // 0..1055
        const int cls = (rid >= 528) ? 1 : 0;
        const int p = rid - cls * 528;
        // decode upper-triangular (ti<=tj) pair index: S(r) = (65r - r^2)/2
#define SFUN(r) ((65 * (r) - (r) * (r)) >> 1)
        int ti = (int)((65.0f - sqrtf(4225.0f - 8.0f * (float)p)) * 0.5f);
        if (ti > 31) ti = 31;
        if (ti < 0) ti = 0;
        while (SFUN(ti + 1) <= p) ++ti;
        while (SFUN(ti) > p) --ti;
        const int tj = ti + (p - SFUN(ti));
#undef SFUN

        const int i0 = cls * KCLS + ti * 64 + wid * 16;
        const int jb = cls * KCLS + tj * 64;

        const _Float16* aip = cnT + (size_t)(i0 + m) * DIM + kg * 8;
        half8 af[4];
#pragma unroll
        for (int tt = 0; tt < 4; ++tt) af[tt] = *(const half8*)(aip + tt * 32);

        half8 bf[16];
#pragma unroll
        for (int fj = 0; fj < 4; ++fj) {
            const _Float16* bjp = cnT + (size_t)(jb + fj * 16 + m) * DIM + kg * 8;
#pragma unroll
            for (int tt = 0; tt < 4; ++tt) bf[fj * 4 + tt] = *(const half8*)(bjp + tt * 32);
        }

        float local = 0.f;
#pragma unroll
        for (int fj = 0; fj < 4; ++fj) {
            f32x4 cc = {0.f, 0.f, 0.f, 0.f};
#pragma unroll
            for (int tt = 0; tt < 4; ++tt)
                cc = __builtin_amdgcn_mfma_f32_16x16x32_f16(af[tt], bf[fj * 4 + tt], cc, 0, 0, 0);
            int gj = jb + fj * 16 + m;
#pragma unroll
            for (int r = 0; r < 4; ++r) {
                int gi = i0 + kg * 4 + r;
                if (gi < gj)
                    local += sqrtf(fmaxf(2.0f + 1e-5f - 2.f * cc[r], 0.f));
            }
        }
#pragma unroll
        for (int off = 1; off < 64; off <<= 1) local += __shfl_xor(local, off);
        if (lane == 0) red[wid] = local;
        __syncthreads();
        if (t == 0) {
            atomicAdd(acc_rg, (red[0] + red[1]) + (red[2] + red[3]));
            FINISH_IF_LAST();
        }
        return;
    }

    // ---------------- kmain path ----------------
    const int rb = id & 127;           // rowgroup: same-row blocks 128 apart -> same XCD
    const int split = id >> 7;         // 0..7
    const int cls = split >> 2;
    const int qz = split & 3;
    const int r0 = rb * 128 + wid * 32;

    // ---- load + normalize 2 x-rows into B fragments ----
    half8 b[2][4];                     // [rowfrag][ks]
#define LOADX(ROW, RF)                                                        \
    do {                                                                      \
        const float* xp = x + (size_t)(ROW)*DIM + kg * 8;                     \
        float xr[4][8];                                                       \
        float ss = 0.f;                                                       \
        _Pragma("unroll") for (int ks = 0; ks < 4; ++ks) {                    \
            float4 f0 = *(const float4*)(xp + ks * 32);                       \
            float4 f1 = *(const float4*)(xp + ks * 32 + 4);                   \
            xr[ks][0] = f0.x; xr[ks][1] = f0.y; xr[ks][2] = f0.z;             \
            xr[ks][3] = f0.w; xr[ks][4] = f1.x; xr[ks][5] = f1.y;             \
            xr[ks][6] = f1.z; xr[ks][7] = f1.w;                               \
            _Pragma("unroll") for (int qq = 0; qq < 8; ++qq)                  \
                ss = fmaf(xr[ks][qq], xr[ks][qq], ss);                        \
        }                                                                     \
        ss += __shfl_xor(ss, 16);                                             \
        ss += __shfl_xor(ss, 32);                                             \
        float rn = G2L / sqrtf(ss);                                           \
        _Pragma("unroll") for (int ks = 0; ks < 4; ++ks)                      \
            _Pragma("unroll") for (int qq = 0; qq < 8; ++qq)                  \
                b[RF][ks][qq] = (_Float16)(xr[ks][qq] * rn);                  \
    } while (0)

    LOADX(r0 + m, 0);
    LOADX(r0 + 16 + m, 1);
#undef LOADX
    // drain x loads so in-loop vmcnt counts ONLY stage DMAs
    asm volatile("s_waitcnt vmcnt(0)" ::: "memory");

    // ---- staging: wave wid stages col-frag cf=wid of each chunk ----
    const int colbase = cls * KCLS + qz * 512;
    const _Float16* sA = cnT + (size_t)(colbase + wid * 16 + m) * DIM + kg * 8;
    const size_t CSTEP = (size_t)64 * DIM;     // 64 cols of halves

#define STAGE(CH, BUF)                                                        \
    do {                                                                      \
        _Pragma("unroll") for (int ks = 0; ks < 4; ++ks)                      \
            GLOAD_LDS(sA + (size_t)(CH) * CSTEP + ks * 32,                    \
                      &smem[BUF][wid][ks][0][0]);                             \
    } while (0)

    float zac[2] = {0.f, 0.f};
    float wac[2] = {0.f, 0.f};

#define COMPUTE(B)                                                            \
    do {                                                                      \
        f32x4 c[2][4];                                                        \
        _Pragma("unroll") for (int rf = 0; rf < 2; ++rf)                      \
            _Pragma("unroll") for (int cf = 0; cf < 4; ++cf)                  \
                c[rf][cf] = (f32x4){0.f, 0.f, 0.f, 0.f};                      \
        __builtin_amdgcn_s_setprio(1);                                        \
        _Pragma("unroll") for (int ks = 0; ks < 4; ++ks) {                    \
            half8 a0 = *(const half8*)&smem[B][0][ks][lane][0];               \
            half8 a1 = *(const half8*)&smem[B][1][ks][lane][0];               \
            half8 a2 = *(const half8*)&smem[B][2][ks][lane][0];               \
            half8 a3 = *(const half8*)&smem[B][3][ks][lane][0];               \
            c[0][0] = __builtin_amdgcn_mfma_f32_16x16x32_f16(a0, b[0][ks], c[0][0], 0, 0, 0); \
            c[1][0] = __builtin_amdgcn_mfma_f32_16x16x32_f16(a0, b[1][ks], c[1][0], 0, 0, 0); \
            c[0][1] = __builtin_amdgcn_mfma_f32_16x16x32_f16(a1, b[0][ks], c[0][1], 0, 0, 0); \
            c[1][1] = __builtin_amdgcn_mfma_f32_16x16x32_f16(a1, b[1][ks], c[1][1], 0, 0, 0); \
            c[0][2] = __builtin_amdgcn_mfma_f32_16x16x32_f16(a2, b[0][ks], c[0][2], 0, 0, 0); \
            c[1][2] = __builtin_amdgcn_mfma_f32_16x16x32_f16(a2, b[1][ks], c[1][2], 0, 0, 0); \
            c[0][3] = __builtin_amdgcn_mfma_f32_16x16x32_f16(a3, b[0][ks], c[0][3], 0, 0, 0); \
            c[1][3] = __builtin_amdgcn_mfma_f32_16x16x32_f16(a3, b[1][ks], c[1][3], 0, 0, 0); \
        }                                                                     \
        __builtin_amdgcn_s_setprio(0);                                        \
        _Pragma("unroll") for (int rf = 0; rf < 2; ++rf) {                    \
            _Pragma("unroll") for (int cf = 0; cf < 4; ++cf) {                \
                float s0 = c[rf][cf][0], s1 = c[rf][cf][1];                   \
                float s2 = c[rf][cf][2], s3 = c[rf][cf][3];                   \
                float e0 = EXP2(s0), e1 = EXP2(s1);                           \
                float e2 = EXP2(s2), e3 = EXP2(s3);                           \
                zac[rf] += (e0 + e1) + (e2 + e3);                             \
                wac[rf] += fmaf(e0, s0, e1 * s1) + fmaf(e2, s2, e3 * s3);     \
            }                                                                 \
        }                                                                     \
    } while (0)

    STAGE(0, 0);

    for (int ch = 0; ch < 8; ++ch) {
        asm volatile("s_waitcnt vmcnt(0)" ::: "memory");  // stage(ch) landed
        __builtin_amdgcn_s_barrier();                     // all waves: stage(ch) landed,
                                                          // compute(ch-1) reads done
        if (ch < 7) STAGE(ch + 1, (ch + 1) & 1);          // flies during compute(ch)
        COMPUTE(ch & 1);
    }
#undef COMPUTE
#undef STAGE

    // merge the 4 kg-groups (disjoint col subsets, plain sums)
#pragma unroll
    for (int rf = 0; rf < 2; ++rf) {
        zac[rf] += __shfl_xor(zac[rf], 16); zac[rf] += __shfl_xor(zac[rf], 32);
        wac[rf] += __shfl_xor(wac[rf], 16); wac[rf] += __shfl_xor(wac[rf], 32);
    }

    // ---- atomic-accumulate partials: pw[(cls*2+comp)*NB + row] ----
    if (lane < 16) {
#pragma unroll
        for (int rf = 0; rf < 2; ++rf) {
            const int row = r0 + rf * 16 + m;
            atomicAdd(&pw[(size_t)(cls * 2 + 0) * NB + row], zac[rf]);
            atomicAdd(&pw[(size_t)(cls * 2 + 1) * NB + row], wac[rf]);
        }
    }
    asm volatile("s_waitcnt vmcnt(0)" ::: "memory");      // own atomics applied
    __syncthreads();                                      // all waves' atomics applied

    // ---- last of the 8 split-blocks for this rowgroup computes CE ----
    if (t == 0) {
        unsigned old = atomicAdd(&rgc[rb], 1u);
        sflag = (old == 7u) ? 1u : 0u;
    }
    __syncthreads();
    if (sflag) {
        float ce = 0.f;
        if (t < 128) {
            const int i = rb * 128 + t;
            float z0 = ALOAD(&pw[(size_t)0 * NB + i]);
            float w0 = ALOAD(&pw[(size_t)1 * NB + i]);
            float z1 = ALOAD(&pw[(size_t)2 * NB + i]);
            float w1 = ALOAD(&pw[(size_t)3 * NB + i]);
            float lg0 = LA * (w0 / (z0 * G2L) - MARGIN);
            float lg1 = LA * (w1 / (z1 * G2L) - MARGIN);
            out[1 + 2 * i] = lg0;
            out[2 + 2 * i] = lg1;
            int tg = tgt[i];
            float mx = fmaxf(lg0, lg1);
            float lse = mx + logf(expf(lg0 - mx) + expf(lg1 - mx));
            ce = lse - (tg ? lg1 : lg0);
        }
#pragma unroll
        for (int off = 1; off < 64; off <<= 1) ce += __shfl_xor(ce, off);
        if ((t & 63) == 0) red[t >> 6] = ce;
        __syncthreads();
        if (t == 0) atomicAdd(acc_ce, red[0] + red[1]);   // waves 2,3 are 0
    }
    if (t == 0) FINISH_IF_LAST();
#undef FINISH_IF_LAST
}

extern "C" void kernel_launch(void* const* d_in, const int* in_sizes, int n_in,
                              void* d_out, int out_size, void* d_ws, size_t ws_size,
                              hipStream_t stream) {
    const float* x  = (const float*)d_in[0];
    const int*   tg = (const int*)d_in[1];
    const float* fc = (const float*)d_in[2];
    float* out = (float*)d_out;
    float* ws  = (float*)d_ws;
    // ws layout: [0..255] accum/counters (1 KB), then cnT (1 MB), then pw (256 KB)
    _Float16* cnT = (_Float16*)(ws + 256);
    float* pw = (float*)(cnT + (size_t)SUMK * DIM);

    knorm<<<SUMK / 32, 256, 0, stream>>>(fc, cnT, ws, pw);
    kbig<<<1024 + 1056, 256, 0, stream>>>(x, cnT, tg, pw, out, ws);
}